// Round 5
// baseline (328.580 us; speedup 1.0000x reference)
//
#include <hip/hip_runtime.h>
#include <hip/hip_bf16.h>

// Problem constants (from reference)
#define BB 32      // batch
#define NN 256     // graph nodes
#define OBS 512
#define HH 256     // hidden = OUT = 256
#define NA 18      // action dim

// ---------------------------------------------------------------------------
// d^{-1/2} per row: d[b,i] = 1/sqrt(max(1, 1 + sum_j adj[b,i,j]))
// one wave (64 lanes) per row
__global__ __launch_bounds__(256) void row_sums_kernel(
    const float* __restrict__ adj, float* __restrict__ dvec)
{
    int gtid = blockIdx.x * blockDim.x + threadIdx.x;
    int wave = gtid >> 6;
    int lane = threadIdx.x & 63;
    if (wave >= BB * NN) return;
    const float* row = adj + (long)wave * NN;
    float s = row[lane] + row[lane + 64] + row[lane + 128] + row[lane + 192];
    #pragma unroll
    for (int m = 32; m; m >>= 1) s += __shfl_xor(s, m);
    if (lane == 0) {
        float t = fmaxf(s + 1.0f, 1.0f);   // +1 for self loop diagonal
        dvec[wave] = 1.0f / sqrtf(t);
    }
}

// nodes_f[b,n,:] = flat[b*T + (n - nn0[b])] if valid writer else nodes0[b,n,:]
__global__ __launch_bounds__(256) void build_nodes_kernel(
    const float* __restrict__ flat, const float* __restrict__ nodes0,
    const int* __restrict__ nn0, int T, float* __restrict__ nodes_out)
{
    int idx = blockIdx.x * 256 + threadIdx.x;   // float4 index over BB*NN*OBS/4
    int k4 = idx & (OBS / 4 - 1);               // 0..127
    int n  = (idx >> 7) & (NN - 1);
    int b  = idx >> 15;
    int n0 = nn0[b];
    int t = -1;
    if (n < NN - 1) {
        int tt = n - n0;
        if (tt >= 0 && tt < T) t = tt;
    } else {
        if (n0 + T - 1 >= NN - 1) t = T - 1;   // clamped writes: last one wins
    }
    const float4* src;
    if (t >= 0) src = (const float4*)(flat + ((long)(b * T + t)) * OBS) + k4;
    else        src = (const float4*)nodes0 + idx;
    ((float4*)nodes_out)[idx] = *src;
}

// ---------------------------------------------------------------------------
// Tiled fp32 GEMM: C = A (MxK) @ Bm (KxN)  (+bias, +relu)
// 64x64 block tile, 16 k-tile, TWO waves (128 threads); each wave owns a
// 64x32 half (8x4 microtile/thread). 512 blocks x 2 waves = 1024 waves =
// 1/SIMD chip-wide (the 64-thread version left half the SIMDs idle).
// LDS balance at 4 waves/CU: 768 LDS-cyc < 1024 FMA-cyc per k-tile.
#define LDP 68   // padded LDS row stride (floats)
template<bool BIAS, bool RELU>
__global__ __launch_bounds__(128) void gemm_tiled(
    const float* __restrict__ A,
    const float* __restrict__ Bm,
    float* __restrict__ C,
    const float* __restrict__ bias,
    int M, int N, int K)
{
    const int bm = blockIdx.y * 64;
    const int bn = blockIdx.x * 64;

    __shared__ float As[16][LDP];   // As[k][m]
    __shared__ float Bs[16][LDP];   // Bs[k][n]

    const int tid  = threadIdx.x;   // 0..127
    const int wv   = tid >> 6;      // 0..1
    const int lane = tid & 63;
    const int ty = lane >> 3;       // 0..7
    const int tx = lane & 7;        // 0..7

    // A loader: 4 lanes cover 64B of one row; rows a_r and a_r+32
    const int a_r = tid >> 2;           // 0..31
    const int a_k = (tid & 3) * 4;      // 0,4,8,12
    // B loader: 16 lanes cover 256B of one k-row; rows b_k and b_k+8
    const int b_k = tid >> 4;           // 0..7
    const int b_c = (tid & 15) * 4;     // 0..60

    float acc[8][4] = {};
    float4 pa[2], pb[2];

    #pragma unroll
    for (int r = 0; r < 2; ++r) {
        pa[r] = *(const float4*)&A[(long)(bm + a_r + r * 32) * K + a_k];
        pb[r] = *(const float4*)&Bm[(long)(b_k + r * 8) * N + bn + b_c];
    }

    for (int k0 = 0; k0 < K; k0 += 16) {
        #pragma unroll
        for (int r = 0; r < 2; ++r) {
            As[a_k + 0][a_r + r * 32] = pa[r].x;
            As[a_k + 1][a_r + r * 32] = pa[r].y;
            As[a_k + 2][a_r + r * 32] = pa[r].z;
            As[a_k + 3][a_r + r * 32] = pa[r].w;
            *(float4*)&Bs[b_k + r * 8][b_c] = pb[r];
        }
        __syncthreads();
        if (k0 + 16 < K) {
            #pragma unroll
            for (int r = 0; r < 2; ++r) {
                pa[r] = *(const float4*)&A[(long)(bm + a_r + r * 32) * K + k0 + 16 + a_k];
                pb[r] = *(const float4*)&Bm[(long)(k0 + 16 + b_k + r * 8) * N + bn + b_c];
            }
        }
        #pragma unroll
        for (int kk = 0; kk < 16; ++kk) {
            float4 a0 = *(const float4*)&As[kk][ty * 8];
            float4 a1 = *(const float4*)&As[kk][ty * 8 + 4];
            float4 b0 = *(const float4*)&Bs[kk][wv * 32 + tx * 4];
            float am[8] = {a0.x, a0.y, a0.z, a0.w, a1.x, a1.y, a1.z, a1.w};
            float bb[4] = {b0.x, b0.y, b0.z, b0.w};
            #pragma unroll
            for (int i = 0; i < 8; ++i)
                #pragma unroll
                for (int j = 0; j < 4; ++j)
                    acc[i][j] = fmaf(am[i], bb[j], acc[i][j]);
        }
        __syncthreads();
    }

    const int colbase = bn + wv * 32 + tx * 4;
    float bia[4] = {};
    if (BIAS) {
        float4 v0 = *(const float4*)&bias[colbase];
        bia[0] = v0.x; bia[1] = v0.y; bia[2] = v0.z; bia[3] = v0.w;
    }
    #pragma unroll
    for (int i = 0; i < 8; ++i) {
        int row = bm + ty * 8 + i;
        float v[4];
        #pragma unroll
        for (int j = 0; j < 4; ++j) {
            v[j] = acc[i][j];
            if (BIAS) v[j] += bia[j];
            if (RELU) v[j] = fmaxf(v[j], 0.f);
        }
        *(float4*)&C[(long)row * N + colbase] = make_float4(v[0], v[1], v[2], v[3]);
    }
}

// ---------------------------------------------------------------------------
// Batched GCN aggregate: C[z] = An[z] @ X[z] (+bias, +relu), An never
// materialized: An[i,j] = d_i*d_j*(adj[i,j] + (i==j)), applied at LDS-store.
template<bool RELU>
__global__ __launch_bounds__(128) void gemm_An(
    const float* __restrict__ adj,   // [B,N,N]
    const float* __restrict__ dvec,  // [B,N]
    const float* __restrict__ X,     // [B,N,H]
    float* __restrict__ C,           // [B,N,H]
    const float* __restrict__ bias)
{
    const int z = blockIdx.z;
    adj += (long)z * NN * NN;
    X   += (long)z * NN * HH;
    C   += (long)z * NN * HH;
    const float* dg = dvec + z * NN;

    const int bm = blockIdx.y * 64;
    const int bn = blockIdx.x * 64;

    __shared__ float As[16][LDP];
    __shared__ float Bs[16][LDP];
    __shared__ float dl[NN];        // all 256 d^{-1/2} values for this batch

    const int tid  = threadIdx.x;
    const int wv   = tid >> 6;
    const int lane = tid & 63;
    const int ty = lane >> 3;
    const int tx = lane & 7;

    const int a_r = tid >> 2;
    const int a_k = (tid & 3) * 4;
    const int b_k = tid >> 4;
    const int b_c = (tid & 15) * 4;

    dl[tid]       = dg[tid];
    dl[tid + 128] = dg[tid + 128];
    __syncthreads();                // 2 waves: visibility needs a barrier

    float acc[8][4] = {};
    float4 pa[2], pb[2];

    #pragma unroll
    for (int r = 0; r < 2; ++r) {
        pa[r] = *(const float4*)&adj[(long)(bm + a_r + r * 32) * NN + a_k];
        pb[r] = *(const float4*)&X[(long)(b_k + r * 8) * HH + bn + b_c];
    }

    for (int k0 = 0; k0 < NN; k0 += 16) {
        #pragma unroll
        for (int r = 0; r < 2; ++r) {
            const int gr = bm + a_r + r * 32;
            const float dr = dl[gr];
            const int gk = k0 + a_k;
            As[a_k + 0][a_r + r * 32] = (pa[r].x + (gr == gk + 0 ? 1.f : 0.f)) * dr * dl[gk + 0];
            As[a_k + 1][a_r + r * 32] = (pa[r].y + (gr == gk + 1 ? 1.f : 0.f)) * dr * dl[gk + 1];
            As[a_k + 2][a_r + r * 32] = (pa[r].z + (gr == gk + 2 ? 1.f : 0.f)) * dr * dl[gk + 2];
            As[a_k + 3][a_r + r * 32] = (pa[r].w + (gr == gk + 3 ? 1.f : 0.f)) * dr * dl[gk + 3];
            *(float4*)&Bs[b_k + r * 8][b_c] = pb[r];
        }
        __syncthreads();
        if (k0 + 16 < NN) {
            #pragma unroll
            for (int r = 0; r < 2; ++r) {
                pa[r] = *(const float4*)&adj[(long)(bm + a_r + r * 32) * NN + k0 + 16 + a_k];
                pb[r] = *(const float4*)&X[(long)(k0 + 16 + b_k + r * 8) * HH + bn + b_c];
            }
        }
        #pragma unroll
        for (int kk = 0; kk < 16; ++kk) {
            float4 a0 = *(const float4*)&As[kk][ty * 8];
            float4 a1 = *(const float4*)&As[kk][ty * 8 + 4];
            float4 b0 = *(const float4*)&Bs[kk][wv * 32 + tx * 4];
            float am[8] = {a0.x, a0.y, a0.z, a0.w, a1.x, a1.y, a1.z, a1.w};
            float bb[4] = {b0.x, b0.y, b0.z, b0.w};
            #pragma unroll
            for (int i = 0; i < 8; ++i)
                #pragma unroll
                for (int j = 0; j < 4; ++j)
                    acc[i][j] = fmaf(am[i], bb[j], acc[i][j]);
        }
        __syncthreads();
    }

    const int colbase = bn + wv * 32 + tx * 4;
    float4 v0 = *(const float4*)&bias[colbase];
    float bia[4] = {v0.x, v0.y, v0.z, v0.w};
    #pragma unroll
    for (int i = 0; i < 8; ++i) {
        int row = bm + ty * 8 + i;
        float v[4];
        #pragma unroll
        for (int j = 0; j < 4; ++j) {
            v[j] = acc[i][j] + bia[j];
            if (RELU) v[j] = fmaxf(v[j], 0.f);
        }
        *(float4*)&C[(long)row * HH + colbase] = make_float4(v[0], v[1], v[2], v[3]);
    }
}

// ---------------------------------------------------------------------------
// out_last[b,c] = b2[c] + sum_j An[b,r,j] * X[b,j,c],  r = min(nn0+T-1, N-1)
// An row built on the fly from adj + dvec.
__global__ __launch_bounds__(256) void final_row_kernel(
    const float* __restrict__ adj, const float* __restrict__ dvec,
    const float* __restrict__ X,
    const float* __restrict__ b2, const int* __restrict__ nn0, int T,
    float* __restrict__ out_last)
{
    int b = blockIdx.x;
    int c = threadIdx.x;
    __shared__ float srow[NN];
    int r = min(nn0[b] + T - 1, NN - 1);
    float dr = dvec[b * NN + r];
    float dc = dvec[b * NN + c];
    float a = adj[((long)b * NN + r) * NN + c] + (r == c ? 1.f : 0.f);
    srow[c] = dr * dc * a;
    __syncthreads();
    float acc = b2[c];
    const float* Xb = X + (long)b * NN * HH;
    #pragma unroll 4
    for (int j = 0; j < NN; ++j) acc = fmaf(srow[j], Xb[j * HH + c], acc);
    out_last[b * HH + c] = acc;
}

// logits[b,T-1,:] = out_last[b] @ Wl + bl ; values[b,T-1] = out_last[b]@Wv + bv
// nn_f[b] = min(nn0[b]+T, N-1)  -- written as FLOAT: the harness reads the
// whole d_out buffer as float32 and compares against float(nn_f).
__global__ __launch_bounds__(64) void head_kernel(
    const float* __restrict__ out_last,
    const float* __restrict__ Wl, const float* __restrict__ bl,
    const float* __restrict__ Wv, const float* __restrict__ bv,
    const int* __restrict__ nn0, int T,
    float* __restrict__ logits, float* __restrict__ values, float* __restrict__ nnf)
{
    int b = blockIdx.x;
    int t = threadIdx.x;
    const float* o = out_last + b * HH;
    if (t < NA) {
        float acc = bl[t];
        for (int k = 0; k < HH; ++k) acc = fmaf(o[k], Wl[k * NA + t], acc);
        logits[((long)b * T + (T - 1)) * NA + t] = acc;
    } else if (t == NA) {
        float acc = bv[0];
        for (int k = 0; k < HH; ++k) acc = fmaf(o[k], Wv[k], acc);
        values[b * T + (T - 1)] = acc;
    } else if (t == NA + 1) {
        nnf[b] = (float)min(nn0[b] + T, NN - 1);   // float, not int bits
    }
}

// ---------------------------------------------------------------------------
extern "C" void kernel_launch(void* const* d_in, const int* in_sizes, int n_in,
                              void* d_out, int out_size, void* d_ws, size_t ws_size,
                              hipStream_t stream) {
    const float* flat   = (const float*)d_in[0];
    const float* nodes0 = (const float*)d_in[1];
    const float* adj0   = (const float*)d_in[2];
    const float* W0     = (const float*)d_in[3];
    const float* b0     = (const float*)d_in[4];
    const float* W1     = (const float*)d_in[5];
    const float* b1     = (const float*)d_in[6];
    const float* W2     = (const float*)d_in[7];
    const float* b2     = (const float*)d_in[8];
    const float* Wl     = (const float*)d_in[9];
    const float* bl     = (const float*)d_in[10];
    const float* Wv     = (const float*)d_in[11];
    const float* bv     = (const float*)d_in[12];
    const int*   nn0    = (const int*)d_in[13];

    const int T = in_sizes[0] / (BB * OBS);   // = 32

    // d_out layout: logits[B*T*NA] | values[B*T] | nodes_f[B*N*OBS] | nn_f[B]
    float* logits  = (float*)d_out;
    float* values  = logits + (long)BB * T * NA;
    float* nodes_f = values + (long)BB * T;
    float* nnf     = nodes_f + (long)BB * NN * OBS;

    // workspace (floats): ws0[B*N*H] | ws1[B*N*H] | dvec[B*N] | out_last[B*H]
    // total ~16.06 MB (An is never materialized)
    float* ws0      = (float*)d_ws;
    float* ws1      = ws0 + (long)BB * NN * HH;
    float* dvec     = ws1 + (long)BB * NN * HH;
    float* out_last = dvec + (long)BB * NN;

    hipMemsetAsync(d_out, 0, (size_t)(BB * T * NA + BB * T) * sizeof(float), stream);

    build_nodes_kernel<<<BB * NN * OBS / 4 / 256, 256, 0, stream>>>(
        flat, nodes0, nn0, T, nodes_f);

    row_sums_kernel<<<BB * NN / 4, 256, 0, stream>>>(adj0, dvec);

    // Layer 1: XW0 = nodes_f @ W0   [8192,512]@[512,256]
    gemm_tiled<false, false><<<dim3(HH / 64, BB * NN / 64, 1), 128, 0, stream>>>(
        nodes_f, W0, ws0, nullptr, BB * NN, HH, OBS);
    // h1 = relu(An @ XW0 + b0)   batched, An fused
    gemm_An<true><<<dim3(HH / 64, NN / 64, BB), 128, 0, stream>>>(
        adj0, dvec, ws0, ws1, b0);
    // Layer 2
    gemm_tiled<false, false><<<dim3(HH / 64, BB * NN / 64, 1), 128, 0, stream>>>(
        ws1, W1, ws0, nullptr, BB * NN, HH, HH);
    gemm_An<true><<<dim3(HH / 64, NN / 64, BB), 128, 0, stream>>>(
        adj0, dvec, ws0, ws1, b1);
    // Layer 3: only XW2 in full; An-product needed for ONE row per batch
    gemm_tiled<false, false><<<dim3(HH / 64, BB * NN / 64, 1), 128, 0, stream>>>(
        ws1, W2, ws0, nullptr, BB * NN, HH, HH);
    final_row_kernel<<<BB, NN, 0, stream>>>(adj0, dvec, ws0, b2, nn0, T, out_last);

    head_kernel<<<BB, 64, 0, stream>>>(out_last, Wl, bl, Wv, bv, nn0, T,
                                       logits, values, nnf);
}

// Round 12
// 208.143 us; speedup vs baseline: 1.5786x; 1.5786x over previous
//
#include <hip/hip_runtime.h>
#include <hip/hip_bf16.h>

// Problem constants (from reference)
#define BB 32      // batch
#define NN 256     // graph nodes
#define OBS 512
#define HH 256     // hidden = OUT = 256
#define NA 18      // action dim

typedef __attribute__((ext_vector_type(8))) short frag16;   // 8 bf16 (4 VGPRs)
typedef __attribute__((ext_vector_type(4))) float fragf;    // 4 fp32 acc

__device__ __forceinline__ unsigned short f2bf(float x) {   // RNE f32->bf16
    unsigned int u = __float_as_uint(x);
    u += 0x7FFFu + ((u >> 16) & 1u);
    return (unsigned short)(u >> 16);
}
__device__ __forceinline__ float bf2f(unsigned short h) {
    return __uint_as_float(((unsigned int)h) << 16);
}

// ---------------------------------------------------------------------------
// Fused prep (1 dispatch instead of 3):
//   blocks [0,4096):    nodes_f closed-form scatter (fp32, exact)
//   blocks [4096,6144): d^{-1/2} row sums (one wave per adj row)
//   blocks [6144,6400): weight transpose fp32 [K][256] -> bf16 [256][K]
__global__ __launch_bounds__(256) void fused_prep(
    const float* __restrict__ flat, const float* __restrict__ nodes0,
    const int* __restrict__ nn0, int T, float* __restrict__ nodes_out,
    const float* __restrict__ adj, float* __restrict__ dvec,
    const float* __restrict__ W0, unsigned short* __restrict__ Wt0,
    const float* __restrict__ W1, unsigned short* __restrict__ Wt1,
    const float* __restrict__ W2, unsigned short* __restrict__ Wt2)
{
    const int blk = blockIdx.x;
    const int tid = threadIdx.x;
    if (blk < 4096) {
        // ---- build_nodes ----
        int idx = blk * 256 + tid;              // float4 index over BB*NN*OBS/4
        int n  = (idx >> 7) & (NN - 1);
        int b  = idx >> 15;
        int k4 = idx & (OBS / 4 - 1);
        int n0 = nn0[b];
        int t = -1;
        if (n < NN - 1) {
            int tt = n - n0;
            if (tt >= 0 && tt < T) t = tt;
        } else {
            if (n0 + T - 1 >= NN - 1) t = T - 1;    // clamped writes: last wins
        }
        const float4* src;
        if (t >= 0) src = (const float4*)(flat + ((long)(b * T + t)) * OBS) + k4;
        else        src = (const float4*)nodes0 + idx;
        ((float4*)nodes_out)[idx] = *src;
    } else if (blk < 6144) {
        // ---- row_sums ----
        int gtid = (blk - 4096) * 256 + tid;
        int wave = gtid >> 6;                   // 0 .. BB*NN-1
        int lane = tid & 63;
        const float* row = adj + (long)wave * NN;
        float s = row[lane] + row[lane + 64] + row[lane + 128] + row[lane + 192];
        #pragma unroll
        for (int m = 32; m; m >>= 1) s += __shfl_xor(s, m);
        if (lane == 0) {
            float t = fmaxf(s + 1.0f, 1.0f);    // +1 self loop
            dvec[wave] = 1.0f / sqrtf(t);
        }
    } else {
        // ---- weight transpose ----
        int wblk = blk - 6144;
        const float* in; unsigned short* out; int K, tile_id;
        if (wblk < 128)      { in = W0; out = Wt0; K = 512; tile_id = wblk; }
        else if (wblk < 192) { in = W1; out = Wt1; K = 256; tile_id = wblk - 128; }
        else                 { in = W2; out = Wt2; K = 256; tile_id = wblk - 192; }
        const int n0 = (tile_id & 7) * 32;
        const int k0 = (tile_id >> 3) * 32;
        __shared__ float tile[32][33];
        const int x = tid & 31;
        const int g = tid >> 5;                 // 0..7
        #pragma unroll
        for (int i = 0; i < 4; ++i)
            tile[g * 4 + i][x] = in[(long)(k0 + g * 4 + i) * 256 + n0 + x];
        __syncthreads();
        #pragma unroll
        for (int i = 0; i < 4; ++i)
            out[(long)(n0 + g * 4 + i) * K + k0 + x] = f2bf(tile[x][g * 4 + i]);
    }
}

// ---------------------------------------------------------------------------
// MFMA GEMM: C[M,256] = A[M,K] @ B[K,256], bf16 inputs, fp32 accum, bf16 out.
// B is given TRANSPOSED bf16 [256][K] so fragment reads are k-contiguous b128.
// Block: 128 threads (2 waves), tile 128(M) x 64(N), BK=32; wave = 64x64 via
// 4x4 MFMA 16x16x32 tiles. Grid always 256 blocks -> every CU gets one.
// A_MODE: 0 = fp32 [M][K]; 1 = fused An from adj fp32 (per-batch z);
//         2 = bf16 [M][256].
// TRANS_OUT: write Xt[z][col][row&255] (for next An-GEMM's B); else [row][col].
// XCD note: blocks sharing an A-panel (or batch z) decode from wids = 8k+c,
// i.e. the same XCD under round-robin dispatch -> A/adj panel stays in one L2.
#define LDA 40   // padded LDS row stride in bf16 (80 B: breaks 16-row bank alias)
template<int A_MODE, bool TRANS_OUT, bool BIASRELU>
__global__ __launch_bounds__(128) void mfma_gemm(
    const void* __restrict__ Ap, const unsigned short* __restrict__ Bp,
    unsigned short* __restrict__ Cp,
    const float* __restrict__ bias, const float* __restrict__ dvec,
    int M, int K)
{
    const int gx = gridDim.x, gy = gridDim.y;
    int wid = blockIdx.x + gx * (blockIdx.y + gy * blockIdx.z);
    int nwg = gx * gy * gridDim.z;           // always 256 here (divisible by 8)
    int swz = (wid & 7) * (nwg >> 3) + (wid >> 3);
    const int bn = (swz % gx) * 64;
    int tmp = swz / gx;
    const int bm = (tmp % gy) * 128;
    const int z  = tmp / gy;

    __shared__ unsigned short As[128 * LDA];
    __shared__ unsigned short Bs[64 * LDA];
    __shared__ float dl[NN];

    const int tid = threadIdx.x;             // 0..127
    const int l = tid & 63, w = tid >> 6;

    if constexpr (A_MODE == 1) {
        dl[tid] = dvec[z * NN + tid];
        dl[tid + 128] = dvec[z * NN + tid + 128];
        __syncthreads();
    }

    const float* Af = (A_MODE == 1)
        ? ((const float*)Ap + (long)z * NN * NN) : (const float*)Ap;
    const unsigned short* Ah = (const unsigned short*)Ap;
    const unsigned short* Bz = (A_MODE == 1) ? (Bp + (long)z * NN * HH) : Bp;

    const int arow = bm + tid;               // A loader: one 32-wide row each
    const int br = tid >> 1;                 // B loader: half-row each
    const int bc = (tid & 1) * 16;

    float4 pa[8]; uint4 pa2[4]; uint4 pbv[2];

    #define LOAD(K0)                                                           \
        if constexpr (A_MODE == 2) {                                           \
            _Pragma("unroll")                                                  \
            for (int i = 0; i < 4; ++i)                                        \
                pa2[i] = *(const uint4*)&Ah[(long)arow * 256 + (K0) + i * 8];  \
        } else {                                                               \
            _Pragma("unroll")                                                  \
            for (int i = 0; i < 8; ++i)                                        \
                pa[i] = *(const float4*)&Af[(long)arow * K + (K0) + i * 4];    \
        }                                                                      \
        _Pragma("unroll")                                                      \
        for (int i = 0; i < 2; ++i)                                            \
            pbv[i] = *(const uint4*)&Bz[(long)(bn + br) * K + (K0) + bc + i * 8];

    #define STORE(K0)                                                          \
        if constexpr (A_MODE == 2) {                                           \
            _Pragma("unroll")                                                  \
            for (int i = 0; i < 4; ++i)                                        \
                *(uint4*)&As[tid * LDA + i * 8] = pa2[i];                      \
        } else if constexpr (A_MODE == 1) {                                    \
            const float drow = dl[arow];                                       \
            _Pragma("unroll")                                                  \
            for (int i = 0; i < 4; ++i) {                                      \
                float va[8] = {pa[2*i].x, pa[2*i].y, pa[2*i].z, pa[2*i].w,     \
                               pa[2*i+1].x, pa[2*i+1].y, pa[2*i+1].z, pa[2*i+1].w}; \
                const int kb = (K0) + i * 8;                                   \
                _Pragma("unroll")                                              \
                for (int e = 0; e < 8; ++e)                                    \
                    va[e] = (va[e] + (arow == kb + e ? 1.f : 0.f)) * drow * dl[kb + e]; \
                uint4 q;                                                       \
                q.x = f2bf(va[0]) | ((unsigned)f2bf(va[1]) << 16);             \
                q.y = f2bf(va[2]) | ((unsigned)f2bf(va[3]) << 16);             \
                q.z = f2bf(va[4]) | ((unsigned)f2bf(va[5]) << 16);             \
                q.w = f2bf(va[6]) | ((unsigned)f2bf(va[7]) << 16);             \
                *(uint4*)&As[tid * LDA + i * 8] = q;                           \
            }                                                                  \
        } else {                                                               \
            _Pragma("unroll")                                                  \
            for (int i = 0; i < 4; ++i) {                                      \
                float4 lo = pa[2*i], hi = pa[2*i+1];                           \
                uint4 q;                                                       \
                q.x = f2bf(lo.x) | ((unsigned)f2bf(lo.y) << 16);               \
                q.y = f2bf(lo.z) | ((unsigned)f2bf(lo.w) << 16);               \
                q.z = f2bf(hi.x) | ((unsigned)f2bf(hi.y) << 16);               \
                q.w = f2bf(hi.z) | ((unsigned)f2bf(hi.w) << 16);               \
                *(uint4*)&As[tid * LDA + i * 8] = q;                           \
            }                                                                  \
        }                                                                      \
        _Pragma("unroll")                                                      \
        for (int i = 0; i < 2; ++i)                                            \
            *(uint4*)&Bs[br * LDA + bc + i * 8] = pbv[i];

    fragf acc[4][4];
    #pragma unroll
    for (int mt = 0; mt < 4; ++mt)
        #pragma unroll
        for (int nt = 0; nt < 4; ++nt)
            acc[mt][nt] = (fragf){0.f, 0.f, 0.f, 0.f};

    LOAD(0)

    for (int k0 = 0; k0 < K; k0 += 32) {
        STORE(k0)
        __syncthreads();
        if (k0 + 32 < K) { LOAD(k0 + 32) }
        // fragments: lane l -> m/n = tile*16 + (l&15), k = (l>>4)*8 + j
        const int koff = (l >> 4) * 8;
        frag16 af[4], bf[4];
        #pragma unroll
        for (int mt = 0; mt < 4; ++mt)
            af[mt] = *(const frag16*)&As[(w * 64 + mt * 16 + (l & 15)) * LDA + koff];
        #pragma unroll
        for (int nt = 0; nt < 4; ++nt)
            bf[nt] = *(const frag16*)&Bs[(nt * 16 + (l & 15)) * LDA + koff];
        #pragma unroll
        for (int mt = 0; mt < 4; ++mt)
            #pragma unroll
            for (int nt = 0; nt < 4; ++nt)
                acc[mt][nt] = __builtin_amdgcn_mfma_f32_16x16x32_bf16(
                    af[mt], bf[nt], acc[mt][nt], 0, 0, 0);
        __syncthreads();
    }

    // C/D layout (m89/m91 verified): col = lane&15, row = (lane>>4)*4 + reg
    #pragma unroll
    for (int nt = 0; nt < 4; ++nt) {
        const int col = bn + nt * 16 + (l & 15);
        float bv_ = 0.f;
        if constexpr (BIASRELU) bv_ = bias[col];
        #pragma unroll
        for (int mt = 0; mt < 4; ++mt) {
            const int rbase = bm + w * 64 + mt * 16 + ((l >> 4) << 2);
            #pragma unroll
            for (int r = 0; r < 4; ++r) {
                float v = acc[mt][nt][r];
                if constexpr (BIASRELU) v = fmaxf(v + bv_, 0.f);
                const int rr = rbase + r;
                long addr;
                if constexpr (TRANS_OUT)
                    addr = ((long)(rr >> 8) * 256 + col) * 256 + (rr & 255);
                else if constexpr (A_MODE == 1)
                    addr = ((long)(z * 256 + rr)) * 256 + col;
                else
                    addr = (long)rr * 256 + col;
                Cp[addr] = f2bf(v);
            }
        }
    }
    #undef LOAD
    #undef STORE
}

// ---------------------------------------------------------------------------
// Fused epilogue (1 dispatch instead of memset + final_row + head):
// block b: zero logits[b,:,:]/values[b,:], compute
// out_last[b,c] = b2[c] + sum_j An[b,r,j]*X[b,j,c] into LDS, then heads + nn_f.
// nn_f written as FLOAT (harness reads whole d_out as one fp32 buffer).
__global__ __launch_bounds__(256) void fused_final(
    const float* __restrict__ adj, const float* __restrict__ dvec,
    const unsigned short* __restrict__ X,
    const float* __restrict__ b2, const int* __restrict__ nn0, int T,
    const float* __restrict__ Wl, const float* __restrict__ bl,
    const float* __restrict__ Wv, const float* __restrict__ bv,
    float* __restrict__ logits, float* __restrict__ values,
    float* __restrict__ nnf)
{
    const int b = blockIdx.x;
    const int c = threadIdx.x;
    __shared__ float srow[NN];
    __shared__ float sout[NN];

    // zero this batch's logits/values (only slot T-1 gets real data)
    for (int i = c; i < 32 * NA; i += 256) logits[(long)b * T * NA + i] = 0.f;
    if (c < T) values[b * T + c] = 0.f;

    const int r = min(nn0[b] + T - 1, NN - 1);
    float a = adj[((long)b * NN + r) * NN + c] + (r == c ? 1.f : 0.f);
    srow[c] = dvec[b * NN + r] * dvec[b * NN + c] * a;
    __syncthreads();

    float acc = b2[c];
    const unsigned short* Xb = X + (long)b * NN * HH;
    #pragma unroll 8
    for (int j = 0; j < NN; ++j) acc = fmaf(srow[j], bf2f(Xb[j * HH + c]), acc);
    sout[c] = acc;
    __syncthreads();

    if (c < NA) {
        float s = bl[c];
        for (int k = 0; k < HH; ++k) s = fmaf(sout[k], Wl[k * NA + c], s);
        logits[((long)b * T + (T - 1)) * NA + c] = s;
    } else if (c == NA) {
        float s = bv[0];
        for (int k = 0; k < HH; ++k) s = fmaf(sout[k], Wv[k], s);
        values[b * T + (T - 1)] = s;
    } else if (c == NA + 1) {
        nnf[b] = (float)min(nn0[b] + T, NN - 1);
    }
}

// ---------------------------------------------------------------------------
extern "C" void kernel_launch(void* const* d_in, const int* in_sizes, int n_in,
                              void* d_out, int out_size, void* d_ws, size_t ws_size,
                              hipStream_t stream) {
    const float* flat   = (const float*)d_in[0];
    const float* nodes0 = (const float*)d_in[1];
    const float* adj0   = (const float*)d_in[2];
    const float* W0     = (const float*)d_in[3];
    const float* b0     = (const float*)d_in[4];
    const float* W1     = (const float*)d_in[5];
    const float* b1     = (const float*)d_in[6];
    const float* W2     = (const float*)d_in[7];
    const float* b2     = (const float*)d_in[8];
    const float* Wl     = (const float*)d_in[9];
    const float* bl     = (const float*)d_in[10];
    const float* Wv     = (const float*)d_in[11];
    const float* bv     = (const float*)d_in[12];
    const int*   nn0    = (const int*)d_in[13];

    const int T = in_sizes[0] / (BB * OBS);   // = 32

    // d_out: logits[B*T*NA] | values[B*T] | nodes_f[B*N*OBS] | nn_f[B]
    float* logits  = (float*)d_out;
    float* values  = logits + (long)BB * T * NA;
    float* nodes_f = values + (long)BB * T;
    float* nnf     = nodes_f + (long)BB * NN * OBS;

    // workspace (~8.9 MB): Wt0|Wt1|Wt2 bf16, Xt bf16[32][256][256],
    // h bf16[32][256][256], dvec f32
    unsigned short* Wt0 = (unsigned short*)d_ws;
    unsigned short* Wt1 = Wt0 + 256 * 512;
    unsigned short* Wt2 = Wt1 + 256 * 256;
    unsigned short* Xt  = Wt2 + 256 * 256;
    unsigned short* h   = Xt + (long)BB * NN * HH;
    float* dvec         = (float*)(h + (long)BB * NN * HH);

    // 1) prep: nodes_f + dvec + weight transposes (one dispatch)
    fused_prep<<<6400, 256, 0, stream>>>(
        flat, nodes0, nn0, T, nodes_f,
        adj0, dvec, W0, Wt0, W1, Wt1, W2, Wt2);

    // 2) L1: Xt = (nodes_f @ W0)^T     [8192,512]x[512,256], fp32 A
    mfma_gemm<0, true, false><<<dim3(4, 64, 1), 128, 0, stream>>>(
        nodes_f, Wt0, Xt, nullptr, nullptr, BB * NN, OBS);
    // 3) h = relu(An @ XW0 + b0)       batched, An fused from adj
    mfma_gemm<1, false, true><<<dim3(4, 2, 32), 128, 0, stream>>>(
        adj0, Xt, h, b0, dvec, NN, NN);
    // 4) L2 weight GEMM
    mfma_gemm<2, true, false><<<dim3(4, 64, 1), 128, 0, stream>>>(
        h, Wt1, Xt, nullptr, nullptr, BB * NN, HH);
    // 5) h = relu(An @ XW1 + b1)
    mfma_gemm<1, false, true><<<dim3(4, 2, 32), 128, 0, stream>>>(
        adj0, Xt, h, b1, dvec, NN, NN);
    // 6) L3: XW2 normal layout into Xt; An-product only for 1 row per batch
    mfma_gemm<2, false, false><<<dim3(4, 64, 1), 128, 0, stream>>>(
        h, Wt2, Xt, nullptr, nullptr, BB * NN, HH);

    // 7) epilogue: zero + final row + heads + nn_f (one dispatch)
    fused_final<<<BB, 256, 0, stream>>>(
        adj0, dvec, Xt, b2, nn0, T, Wl, bl, Wv, bv, logits, values, nnf);
}

// Round 16
// 164.559 us; speedup vs baseline: 1.9967x; 1.2649x over previous
//
#include <hip/hip_runtime.h>
#include <hip/hip_bf16.h>

// Problem constants (from reference)
#define BB 32      // batch
#define NN 256     // graph nodes
#define OBS 512
#define HH 256     // hidden = OUT = 256
#define NA 18      // action dim

typedef __attribute__((ext_vector_type(8))) short frag16;   // 8 bf16 (4 VGPRs)
typedef __attribute__((ext_vector_type(4))) float fragf;    // 4 fp32 acc

__device__ __forceinline__ unsigned short f2bf(float x) {   // RNE f32->bf16
    unsigned int u = __float_as_uint(x);
    u += 0x7FFFu + ((u >> 16) & 1u);
    return (unsigned short)(u >> 16);
}
__device__ __forceinline__ float bf2f(unsigned short h) {
    return __uint_as_float(((unsigned int)h) << 16);
}

// ---------------------------------------------------------------------------
// Fused prep (1 dispatch):
//   blocks [0,4096):    nodes_f closed-form scatter (fp32, exact)
//   blocks [4096,6144): d^{-1/2} row sums (one wave per adj row)
//   blocks [6144,6400): weight transpose fp32 [K][256] -> bf16 [256][K]
__global__ __launch_bounds__(256) void fused_prep(
    const float* __restrict__ flat, const float* __restrict__ nodes0,
    const int* __restrict__ nn0, int T, float* __restrict__ nodes_out,
    const float* __restrict__ adj, float* __restrict__ dvec,
    const float* __restrict__ W0, unsigned short* __restrict__ Wt0,
    const float* __restrict__ W1, unsigned short* __restrict__ Wt1,
    const float* __restrict__ W2, unsigned short* __restrict__ Wt2)
{
    const int blk = blockIdx.x;
    const int tid = threadIdx.x;
    if (blk < 4096) {
        int idx = blk * 256 + tid;              // float4 index over BB*NN*OBS/4
        int n  = (idx >> 7) & (NN - 1);
        int b  = idx >> 15;
        int k4 = idx & (OBS / 4 - 1);
        int n0 = nn0[b];
        int t = -1;
        if (n < NN - 1) {
            int tt = n - n0;
            if (tt >= 0 && tt < T) t = tt;
        } else {
            if (n0 + T - 1 >= NN - 1) t = T - 1;    // clamped writes: last wins
        }
        const float4* src;
        if (t >= 0) src = (const float4*)(flat + ((long)(b * T + t)) * OBS) + k4;
        else        src = (const float4*)nodes0 + idx;
        ((float4*)nodes_out)[idx] = *src;
    } else if (blk < 6144) {
        int gtid = (blk - 4096) * 256 + tid;
        int wave = gtid >> 6;                   // 0 .. BB*NN-1
        int lane = tid & 63;
        const float* row = adj + (long)wave * NN;
        float s = row[lane] + row[lane + 64] + row[lane + 128] + row[lane + 192];
        #pragma unroll
        for (int m = 32; m; m >>= 1) s += __shfl_xor(s, m);
        if (lane == 0) {
            float t = fmaxf(s + 1.0f, 1.0f);    // +1 self loop
            dvec[wave] = 1.0f / sqrtf(t);
        }
    } else {
        int wblk = blk - 6144;
        const float* in; unsigned short* out; int K, tile_id;
        if (wblk < 128)      { in = W0; out = Wt0; K = 512; tile_id = wblk; }
        else if (wblk < 192) { in = W1; out = Wt1; K = 256; tile_id = wblk - 128; }
        else                 { in = W2; out = Wt2; K = 256; tile_id = wblk - 192; }
        const int n0 = (tile_id & 7) * 32;
        const int k0 = (tile_id >> 3) * 32;
        __shared__ float tile[32][33];
        const int x = tid & 31;
        const int g = tid >> 5;                 // 0..7
        #pragma unroll
        for (int i = 0; i < 4; ++i)
            tile[g * 4 + i][x] = in[(long)(k0 + g * 4 + i) * 256 + n0 + x];
        __syncthreads();
        #pragma unroll
        for (int i = 0; i < 4; ++i)
            out[(long)(n0 + g * 4 + i) * K + k0 + x] = f2bf(tile[x][g * 4 + i]);
    }
}

// ---------------------------------------------------------------------------
// MFMA GEMM v2 (occupancy fix): C[M,256] = A[M,K] @ B[K,256].
// Round-12 PMC lesson: 128-thr blocks x 256 grid = 0.5 waves/SIMD -> fully
// latency-bound (~30us/GEMM). Now: 256 threads (4 waves), 64x64 tile, BK=32,
// grid = 512 blocks -> 2 blocks/CU, 8 waves/CU = 2/SIMD, 2 indep load streams.
// Wave w owns 32x32 quadrant ((w>>1),(w&1)): acc[2][2], 4 MFMA/k-step.
// A_MODE: 0 = fp32 [M][K]; 1 = fused An from adj fp32 (batch z); 2 = bf16.
// TRANS_OUT: write Xt[z][col][row&255]; else [row][col].
#define LDA 40   // padded LDS row stride in bf16 (80 B)
template<int A_MODE, bool TRANS_OUT, bool BIASRELU>
__global__ __launch_bounds__(256) void mfma_gemm(
    const void* __restrict__ Ap, const unsigned short* __restrict__ Bp,
    unsigned short* __restrict__ Cp,
    const float* __restrict__ bias, const float* __restrict__ dvec,
    int M, int K)
{
    const int gx = gridDim.x, gy = gridDim.y;
    int wid = blockIdx.x + gx * (blockIdx.y + gy * blockIdx.z);
    int nwg = gx * gy * gridDim.z;           // 512 here (divisible by 8)
    int swz = (wid & 7) * (nwg >> 3) + (wid >> 3);
    const int bn = (swz % gx) * 64;
    int tmp = swz / gx;
    const int bm = (tmp % gy) * 64;
    const int z  = tmp / gy;

    __shared__ unsigned short As[64 * LDA];
    __shared__ unsigned short Bs[64 * LDA];
    __shared__ float dl[NN];

    const int tid = threadIdx.x;             // 0..255
    const int l = tid & 63, w = tid >> 6;    // wave 0..3

    if constexpr (A_MODE == 1) {
        dl[tid] = dvec[z * NN + tid];        // 256 threads cover NN
        __syncthreads();
    }

    const float* Af = (A_MODE == 1)
        ? ((const float*)Ap + (long)z * NN * NN) : (const float*)Ap;
    const unsigned short* Ah = (const unsigned short*)Ap;
    const unsigned short* Bz = (A_MODE == 1) ? (Bp + (long)z * NN * HH) : Bp;

    const int a_r = tid >> 2;                // 0..63 (A row / B col)
    const int a_k = (tid & 3) * 8;           // 0,8,16,24
    const int arow = bm + a_r;

    float4 pa[2]; uint4 pa2; uint4 pbv;

    #define LOAD(K0)                                                           \
        if constexpr (A_MODE == 2) {                                           \
            pa2 = *(const uint4*)&Ah[(long)arow * 256 + (K0) + a_k];           \
        } else {                                                               \
            pa[0] = *(const float4*)&Af[(long)arow * K + (K0) + a_k];          \
            pa[1] = *(const float4*)&Af[(long)arow * K + (K0) + a_k + 4];      \
        }                                                                      \
        pbv = *(const uint4*)&Bz[(long)(bn + a_r) * K + (K0) + a_k];

    #define STORE(K0)                                                          \
        if constexpr (A_MODE == 2) {                                           \
            *(uint4*)&As[a_r * LDA + a_k] = pa2;                               \
        } else if constexpr (A_MODE == 1) {                                    \
            const float drow = dl[arow];                                       \
            float va[8] = {pa[0].x, pa[0].y, pa[0].z, pa[0].w,                 \
                           pa[1].x, pa[1].y, pa[1].z, pa[1].w};                \
            const int kb = (K0) + a_k;                                         \
            _Pragma("unroll")                                                  \
            for (int e = 0; e < 8; ++e)                                        \
                va[e] = (va[e] + (arow == kb + e ? 1.f : 0.f)) * drow * dl[kb + e]; \
            uint4 q;                                                           \
            q.x = f2bf(va[0]) | ((unsigned)f2bf(va[1]) << 16);                 \
            q.y = f2bf(va[2]) | ((unsigned)f2bf(va[3]) << 16);                 \
            q.z = f2bf(va[4]) | ((unsigned)f2bf(va[5]) << 16);                 \
            q.w = f2bf(va[6]) | ((unsigned)f2bf(va[7]) << 16);                 \
            *(uint4*)&As[a_r * LDA + a_k] = q;                                 \
        } else {                                                               \
            uint4 q;                                                           \
            q.x = f2bf(pa[0].x) | ((unsigned)f2bf(pa[0].y) << 16);             \
            q.y = f2bf(pa[0].z) | ((unsigned)f2bf(pa[0].w) << 16);             \
            q.z = f2bf(pa[1].x) | ((unsigned)f2bf(pa[1].y) << 16);             \
            q.w = f2bf(pa[1].z) | ((unsigned)f2bf(pa[1].w) << 16);             \
            *(uint4*)&As[a_r * LDA + a_k] = q;                                 \
        }                                                                      \
        *(uint4*)&Bs[a_r * LDA + a_k] = pbv;

    fragf acc[2][2];
    #pragma unroll
    for (int mt = 0; mt < 2; ++mt)
        #pragma unroll
        for (int nt = 0; nt < 2; ++nt)
            acc[mt][nt] = (fragf){0.f, 0.f, 0.f, 0.f};

    LOAD(0)

    const int wm = (w >> 1) * 32;            // wave's m-quadrant
    const int wn = (w & 1) * 32;             // wave's n-quadrant
    const int koff = (l >> 4) * 8;

    for (int k0 = 0; k0 < K; k0 += 32) {
        STORE(k0)
        __syncthreads();
        if (k0 + 32 < K) { LOAD(k0 + 32) }
        frag16 af[2], bf[2];
        #pragma unroll
        for (int mt = 0; mt < 2; ++mt)
            af[mt] = *(const frag16*)&As[(wm + mt * 16 + (l & 15)) * LDA + koff];
        #pragma unroll
        for (int nt = 0; nt < 2; ++nt)
            bf[nt] = *(const frag16*)&Bs[(wn + nt * 16 + (l & 15)) * LDA + koff];
        #pragma unroll
        for (int mt = 0; mt < 2; ++mt)
            #pragma unroll
            for (int nt = 0; nt < 2; ++nt)
                acc[mt][nt] = __builtin_amdgcn_mfma_f32_16x16x32_bf16(
                    af[mt], bf[nt], acc[mt][nt], 0, 0, 0);
        __syncthreads();
    }

    // C/D layout (m89/m91): col = lane&15, row = (lane>>4)*4 + reg
    #pragma unroll
    for (int nt = 0; nt < 2; ++nt) {
        const int col = bn + wn + nt * 16 + (l & 15);
        float bv_ = 0.f;
        if constexpr (BIASRELU) bv_ = bias[col];
        #pragma unroll
        for (int mt = 0; mt < 2; ++mt) {
            const int rbase = bm + wm + mt * 16 + ((l >> 4) << 2);
            #pragma unroll
            for (int r = 0; r < 4; ++r) {
                float v = acc[mt][nt][r];
                if constexpr (BIASRELU) v = fmaxf(v + bv_, 0.f);
                const int rr = rbase + r;
                long addr;
                if constexpr (TRANS_OUT)
                    addr = ((long)(rr >> 8) * 256 + col) * 256 + (rr & 255);
                else if constexpr (A_MODE == 1)
                    addr = ((long)(z * 256 + rr)) * 256 + col;
                else
                    addr = (long)rr * 256 + col;
                Cp[addr] = f2bf(v);
            }
        }
    }
    #undef LOAD
    #undef STORE
}

// ---------------------------------------------------------------------------
// Fused epilogue: zero + final row + heads + nn_f (as float) in one dispatch.
__global__ __launch_bounds__(256) void fused_final(
    const float* __restrict__ adj, const float* __restrict__ dvec,
    const unsigned short* __restrict__ X,
    const float* __restrict__ b2, const int* __restrict__ nn0, int T,
    const float* __restrict__ Wl, const float* __restrict__ bl,
    const float* __restrict__ Wv, const float* __restrict__ bv,
    float* __restrict__ logits, float* __restrict__ values,
    float* __restrict__ nnf)
{
    const int b = blockIdx.x;
    const int c = threadIdx.x;
    __shared__ float srow[NN];
    __shared__ float sout[NN];

    for (int i = c; i < 32 * NA; i += 256) logits[(long)b * T * NA + i] = 0.f;
    if (c < T) values[b * T + c] = 0.f;

    const int r = min(nn0[b] + T - 1, NN - 1);
    float a = adj[((long)b * NN + r) * NN + c] + (r == c ? 1.f : 0.f);
    srow[c] = dvec[b * NN + r] * dvec[b * NN + c] * a;
    __syncthreads();

    float acc = b2[c];
    const unsigned short* Xb = X + (long)b * NN * HH;
    #pragma unroll 8
    for (int j = 0; j < NN; ++j) acc = fmaf(srow[j], bf2f(Xb[j * HH + c]), acc);
    sout[c] = acc;
    __syncthreads();

    if (c < NA) {
        float s = bl[c];
        for (int k = 0; k < HH; ++k) s = fmaf(sout[k], Wl[k * NA + c], s);
        logits[((long)b * T + (T - 1)) * NA + c] = s;
    } else if (c == NA) {
        float s = bv[0];
        for (int k = 0; k < HH; ++k) s = fmaf(sout[k], Wv[k], s);
        values[b * T + (T - 1)] = s;
    } else if (c == NA + 1) {
        nnf[b] = (float)min(nn0[b] + T, NN - 1);
    }
}

// ---------------------------------------------------------------------------
extern "C" void kernel_launch(void* const* d_in, const int* in_sizes, int n_in,
                              void* d_out, int out_size, void* d_ws, size_t ws_size,
                              hipStream_t stream) {
    const float* flat   = (const float*)d_in[0];
    const float* nodes0 = (const float*)d_in[1];
    const float* adj0   = (const float*)d_in[2];
    const float* W0     = (const float*)d_in[3];
    const float* b0     = (const float*)d_in[4];
    const float* W1     = (const float*)d_in[5];
    const float* b1     = (const float*)d_in[6];
    const float* W2     = (const float*)d_in[7];
    const float* b2     = (const float*)d_in[8];
    const float* Wl     = (const float*)d_in[9];
    const float* bl     = (const float*)d_in[10];
    const float* Wv     = (const float*)d_in[11];
    const float* bv     = (const float*)d_in[12];
    const int*   nn0    = (const int*)d_in[13];

    const int T = in_sizes[0] / (BB * OBS);   // = 32

    // d_out: logits[B*T*NA] | values[B*T] | nodes_f[B*N*OBS] | nn_f[B]
    float* logits  = (float*)d_out;
    float* values  = logits + (long)BB * T * NA;
    float* nodes_f = values + (long)BB * T;
    float* nnf     = nodes_f + (long)BB * NN * OBS;

    // workspace (~8.9 MB): Wt0|Wt1|Wt2 bf16, Xt bf16[32][256][256],
    // h bf16[32][256][256], dvec f32
    unsigned short* Wt0 = (unsigned short*)d_ws;
    unsigned short* Wt1 = Wt0 + 256 * 512;
    unsigned short* Wt2 = Wt1 + 256 * 256;
    unsigned short* Xt  = Wt2 + 256 * 256;
    unsigned short* h   = Xt + (long)BB * NN * HH;
    float* dvec         = (float*)(h + (long)BB * NN * HH);

    // 1) prep: nodes_f + dvec + weight transposes (one dispatch)
    fused_prep<<<6400, 256, 0, stream>>>(
        flat, nodes0, nn0, T, nodes_f,
        adj0, dvec, W0, Wt0, W1, Wt1, W2, Wt2);

    // 2) L1: Xt = (nodes_f @ W0)^T     [8192,512]x[512,256], fp32 A
    mfma_gemm<0, true, false><<<dim3(4, 128, 1), 256, 0, stream>>>(
        nodes_f, Wt0, Xt, nullptr, nullptr, BB * NN, OBS);
    // 3) h = relu(An @ XW0 + b0)       batched, An fused from adj
    mfma_gemm<1, false, true><<<dim3(4, 4, 32), 256, 0, stream>>>(
        adj0, Xt, h, b0, dvec, NN, NN);
    // 4) L2 weight GEMM
    mfma_gemm<2, true, false><<<dim3(4, 128, 1), 256, 0, stream>>>(
        h, Wt1, Xt, nullptr, nullptr, BB * NN, HH);
    // 5) h = relu(An @ XW1 + b1)
    mfma_gemm<1, false, true><<<dim3(4, 4, 32), 256, 0, stream>>>(
        adj0, Xt, h, b1, dvec, NN, NN);
    // 6) L3: XW2 normal layout into Xt; An-product only for 1 row per batch
    mfma_gemm<2, false, false><<<dim3(4, 128, 1), 256, 0, stream>>>(
        h, Wt2, Xt, nullptr, nullptr, BB * NN, HH);

    // 7) epilogue: zero + final row + heads + nn_f (one dispatch)
    fused_final<<<BB, 256, 0, stream>>>(
        adj0, dvec, Xt, b2, nn0, T, Wl, bl, Wv, bv, logits, values, nnf);
}